// Round 5
// baseline (254.696 us; speedup 1.0000x reference)
//
#include <hip/hip_runtime.h>
#include <hip/hip_fp16.h>
#include <math.h>

#define SEQ    1024
#define DK     16
#define NHEAD  16
#define NBATCH 8
#define LOG2E  1.4426950408889634f
#define NEGBIG -60000.0f

#define CH     64                        // keys per LDS chunk
#define NCH    (SEQ / CH)                // 16 chunks
#define KHI_STRIDE 32                    // LDS bytes per key row (no pad; XOR swizzle)
#define VT_STRIDE  128                   // LDS bytes per d row   (no pad; XOR swizzle)
#define KHI_CH (CH * KHI_STRIDE)         // 2048 B
#define VT_CH  (DK * VT_STRIDE)          // 2048 B
#define BIAS_CH (128 * CH * 2)           // 16384 B (128 q-rows x 64 keys, fp16)
#define BUF_SZ (KHI_CH + VT_CH + BIAS_CH)// 20480 B per buffer (x2 = 40960 -> 4 blk/CU)

typedef __attribute__((ext_vector_type(4))) short  short4v;
typedef __attribute__((ext_vector_type(8))) short  short8v;
typedef __attribute__((ext_vector_type(2))) short  short2v;
typedef __attribute__((ext_vector_type(4))) float  float4v;
typedef __attribute__((ext_vector_type(2))) unsigned int uint2v;

static __device__ __forceinline__ float fast_exp2(float x) {
#if __has_builtin(__builtin_amdgcn_exp2f)
    return __builtin_amdgcn_exp2f(x);
#else
    return exp2f(x);
#endif
}

static __device__ __forceinline__ float4v mfma16(short4v a, short4v b, float4v c) {
#if __has_builtin(__builtin_amdgcn_mfma_f32_16x16x16bf16_1k)
    return __builtin_amdgcn_mfma_f32_16x16x16bf16_1k(a, b, c, 0, 0, 0);
#else
    float4v d = c;
    asm volatile("v_mfma_f32_16x16x16_bf16 %0, %1, %2, %0" : "+v"(d) : "v"(a), "v"(b));
    return d;
#endif
}

// K=32 MFMA: A/B = 8 bf16/lane (k = quad*8 + j). Fallback: two K=16 halves.
static __device__ __forceinline__ float4v mfma32(short8v a, short8v b, float4v c) {
#if __has_builtin(__builtin_amdgcn_mfma_f32_16x16x32_bf16)
    return __builtin_amdgcn_mfma_f32_16x16x32_bf16(a, b, c, 0, 0, 0);
#else
    short4v a0 = {a[0], a[1], a[2], a[3]}, a1 = {a[4], a[5], a[6], a[7]};
    short4v b0 = {b[0], b[1], b[2], b[3]}, b1 = {b[4], b[5], b[6], b[7]};
    c = mfma16(a0, b0, c);
    return mfma16(a1, b1, c);
#endif
}

static __device__ __forceinline__ unsigned bf16_rne(float x) {
    unsigned u = __float_as_uint(x);
    return (u + 0x7FFFu + ((u >> 16) & 1u)) >> 16;
}
static __device__ __forceinline__ float bf16_to_f(unsigned b) {
    return __uint_as_float(b << 16);
}
static __device__ __forceinline__ unsigned pk_bf16(float a, float b) {
#if __has_builtin(__builtin_amdgcn_cvt_pk_bf16_f32)
    short2v r = __builtin_amdgcn_cvt_pk_bf16_f32(a, b);
    return __builtin_bit_cast(unsigned, r);
#else
    return bf16_rne(a) | (bf16_rne(b) << 16);
#endif
}
static __device__ __forceinline__ short4v bc_s4(unsigned lo, unsigned hi) {
    uint2v u; u.x = lo; u.y = hi;
    return __builtin_bit_cast(short4v, u);
}

// ---------------- Fully fused flash pass -------------------------------------
// Round-5 changes vs round-4 (compute core untouched):
//  * LDS per block 42496 -> 40960 (pad-free K/V with XOR swizzles) so FOUR
//    blocks/CU fit (4 x 40960 = 163840 = full LDS) — kills the 4th-block
//    straggler generation (occupancy was 21.7%).
//  * Bias fragment swizzle sigma(n,g) = g*16 + (n^g): staging ds_write_b64
//    goes 4-way -> 2-way (free); read stays sequential per quarter-wave.
//    (Round-4 counter: SQ_LDS_BANK_CONFLICT 9.2M = 13% of kernel cycles.)
//  * K LDS: stride 32, slot-swizzle (hh ^ ((row>>3)&1)) — write is perfectly
//    sequential (tid*16), read 2-way (free, same grade as old pad-40).
//  * V LDS: stride 128, octet-swizzle (octet ^ (row&7)) — same conflict grade
//    as old pad-144 layout, saves the pad bytes.
__global__ __launch_bounds__(256, 4)
void sdpa_fused(const float* __restrict__ Q, const float* __restrict__ K,
                const float* __restrict__ V, const int* __restrict__ mask,
                const float* __restrict__ bias, float* __restrict__ out) {
    __shared__ __align__(16) char smem[2][BUF_SZ];

    const int tid  = threadIdx.x;
    const int wave = tid >> 6;
    const int lane = tid & 63;
    const int n    = lane & 15;
    const int g    = lane >> 4;
    const int permn = ((n >> 2) << 3) | (n & 3);   // tile-pair key permutation
    const int lso  = (g * 16 + (n ^ g)) * 16;      // bias slot byte off (swizzled)

    const int b  = blockIdx.x & 7;                 // XCD = batch
    const int j  = blockIdx.x >> 3;                // 0..127
    const int h  = j & 15;                         // heads fastest (bias L2 share)
    const int qt = j >> 4;                         // 0..7
    const int q0 = qt * 128;
    const size_t bh = (size_t)b * NHEAD + h;

    // ---- Q fragments (hi/lo split; exact QK via 2 MFMAs) ----
    short4v qh[2], ql[2];
    #pragma unroll
    for (int f = 0; f < 2; ++f) {
        const int qrow = q0 + f * 64 + wave * 16 + n;
        const float4 qv = *(const float4*)(Q + (bh * SEQ + qrow) * DK + g * 4);
        const float qsc = 0.25f * LOG2E;
        const float v[4] = {qv.x * qsc, qv.y * qsc, qv.z * qsc, qv.w * qsc};
        #pragma unroll
        for (int e = 0; e < 4; ++e) {
            const unsigned hu = bf16_rne(v[e]);
            qh[f][e] = (short)hu;
            ql[f][e] = (short)bf16_rne(v[e] - bf16_to_f(hu));
        }
    }

    const float* Kb = K + bh * SEQ * DK;
    const float* Vb = V + bh * SEQ * DK;

    // K/V staging roles (wave-uniform split):
    const int skey = tid >> 1, shh = tid & 1;                 // tid < 128 : K
    const int sk2  = (tid - 128) >> 2, sdq = (tid - 128) & 3; // tid >= 128 : V

    // bias stager coords: thread -> (row group brow, key-quad kq4)
    const int brow = tid >> 4;                 // 0..15
    const int kq4  = tid & 15;                 // float4 index in 64-key chunk
    const int tpo  = kq4 >> 3;                 // tile-pair
    const int g_s  = (kq4 >> 1) & 3;           // key-octet
    const int half_s = kq4 & 1;                // low/high 4 keys of octet
    const int up   = g_s * 16 + (brow ^ g_s);  // swizzled 16B slot (matches lso)
    const int boff = up * 16 + half_s * 8;
    const float* bRow0 = bias + (size_t)b * SEQ * SEQ + (size_t)(q0 + brow) * SEQ + kq4 * 4;
    const int*   mRow0 = mask + (size_t)b * SEQ * SEQ + (size_t)(q0 + brow) * SEQ + kq4 * 4;

    float4v acc[2], accl[2];
    acc[0]  = (float4v){0.f, 0.f, 0.f, 0.f};
    acc[1]  = (float4v){0.f, 0.f, 0.f, 0.f};
    accl[0] = (float4v){0.f, 0.f, 0.f, 0.f};
    accl[1] = (float4v){0.f, 0.f, 0.f, 0.f};
    const short8v ones8 = {(short)0x3F80, (short)0x3F80, (short)0x3F80, (short)0x3F80,
                           (short)0x3F80, (short)0x3F80, (short)0x3F80, (short)0x3F80};

    float4 pb[8]; int4 pm[8];                  // in-flight bias/mask (8 passes)
    float4 kv0, kv1;                           // in-flight K or V

    auto issue = [&](int kc) {
        #pragma unroll
        for (int p = 0; p < 8; ++p) {
            pb[p] = *(const float4*)(bRow0 + (size_t)p * 16 * SEQ + kc);
            pm[p] = *(const int4*)  (mRow0 + (size_t)p * 16 * SEQ + kc);
        }
        if (tid < 128) {
            kv0 = *(const float4*)(Kb + (kc + skey) * DK + shh * 8);
            kv1 = *(const float4*)(Kb + (kc + skey) * DK + shh * 8 + 4);
        } else {
            kv0 = *(const float4*)(Vb + (kc + 2 * sk2) * DK + sdq * 4);
            kv1 = *(const float4*)(Vb + (kc + 2 * sk2 + 1) * DK + sdq * 4);
        }
    };

    auto commit = [&](char* s) {
        if (tid < 128) {
            uint4 kp;
            kp.x = pk_bf16(kv0.x, kv0.y); kp.y = pk_bf16(kv0.z, kv0.w);
            kp.z = pk_bf16(kv1.x, kv1.y); kp.w = pk_bf16(kv1.z, kv1.w);
            // physical(row,hh) = row*32 + (hh ^ ((row>>3)&1))*16  -> write = tid*16-ish
            *(uint4*)(s + skey * KHI_STRIDE + ((shh ^ ((skey >> 3) & 1)) * 16)) = kp;
        } else {
            char* sv = s + KHI_CH;
            const float* pa = (const float*)&kv0;
            const float* pv = (const float*)&kv1;
            #pragma unroll
            for (int jj = 0; jj < 4; ++jj) {
                const int row = 4 * sdq + jj;
                // physical octet = (sk2>>2) ^ (row&7)
                *(unsigned*)(sv + row * VT_STRIDE +
                             (((sk2 >> 2) ^ (row & 7)) * 16) + (sk2 & 3) * 4) =
                    pk_bf16(pa[jj], pv[jj]);
            }
        }
        char* bs = s + KHI_CH + VT_CH;
        #pragma unroll
        for (int p = 0; p < 8; ++p) {
            const float4 bv = pb[p]; const int4 mv = pm[p];
            const __half2 lo = __floats2half2_rn(mv.x ? NEGBIG : bv.x * LOG2E,
                                                 mv.y ? NEGBIG : bv.y * LOG2E);
            const __half2 hi = __floats2half2_rn(mv.z ? NEGBIG : bv.z * LOG2E,
                                                 mv.w ? NEGBIG : bv.w * LOG2E);
            uint2 u;
            u.x = __builtin_bit_cast(unsigned, lo);
            u.y = __builtin_bit_cast(unsigned, hi);
            // block index (f*2+tp)*4 + w  ->  f = p>>2, w = p&3
            *(uint2*)(bs + ((p >> 2) * 2 + tpo) * 4096 + (p & 3) * 1024 + boff) = u;
        }
    };

    // prologue: stage chunk 0
    issue(0);
    commit(smem[0]);
    __syncthreads();

    for (int c = 0; c < NCH; ++c) {
        const int cur = c & 1;
        if (c < NCH - 1) issue((c + 1) * CH);   // chunk-distance prefetch
#if __has_builtin(__builtin_amdgcn_sched_barrier)
        __builtin_amdgcn_sched_barrier(0);      // pin loads above compute
#endif
        const char* khl = smem[cur];
        const char* vtl = smem[cur] + KHI_CH;
        const char* bsl = smem[cur] + KHI_CH + VT_CH;

        #pragma unroll
        for (int tp = 0; tp < 2; ++tp) {
            const int rowA = tp * 32 + permn;
            const int rowB = rowA + 4;
            const int swA = (rowA >> 3) & 1;
            const int swB = (rowB >> 3) & 1;
            const uint2 kAu = *(const uint2*)(khl + rowA * KHI_STRIDE +
                                              (((g >> 1) ^ swA) * 16) + (g & 1) * 8);
            const uint2 kBu = *(const uint2*)(khl + rowB * KHI_STRIDE +
                                              (((g >> 1) ^ swB) * 16) + (g & 1) * 8);
            const uint4 vv  = *(const uint4*)(vtl + n * VT_STRIDE +
                                              (((tp * 4 + g) ^ (n & 7)) * 16));
            const short4v khiA = bc_s4(kAu.x, kAu.y);
            const short4v khiB = bc_s4(kBu.x, kBu.y);
            const short8v vt8  = __builtin_bit_cast(short8v, vv);

            #pragma unroll
            for (int f = 0; f < 2; ++f) {
                const uint4 bb = *(const uint4*)(bsl + ((f * 2 + tp) * 4 + wave) * 1024 + lso);
                const float2 a01 = __half22float2(__builtin_bit_cast(__half2, bb.x));
                const float2 a23 = __half22float2(__builtin_bit_cast(__half2, bb.y));
                float4v sA; sA[0] = a01.x; sA[1] = a01.y; sA[2] = a23.x; sA[3] = a23.y;
                sA = mfma16(khiA, qh[f], sA);
                sA = mfma16(khiA, ql[f], sA);
                const float2 b01 = __half22float2(__builtin_bit_cast(__half2, bb.z));
                const float2 b23 = __half22float2(__builtin_bit_cast(__half2, bb.w));
                float4v sB; sB[0] = b01.x; sB[1] = b01.y; sB[2] = b23.x; sB[3] = b23.y;
                sB = mfma16(khiB, qh[f], sB);
                sB = mfma16(khiB, ql[f], sB);

                const float pA0 = fast_exp2(sA[0]), pA1 = fast_exp2(sA[1]);
                const float pA2 = fast_exp2(sA[2]), pA3 = fast_exp2(sA[3]);
                const float pB0 = fast_exp2(sB[0]), pB1 = fast_exp2(sB[1]);
                const float pB2 = fast_exp2(sB[2]), pB3 = fast_exp2(sB[3]);

                // K=32 A-frag: [pA0..3, pB0..3] == keys 8g..8g+7 (k = quad*8+j)
                uint4 pu;
                pu.x = pk_bf16(pA0, pA1);
                pu.y = pk_bf16(pA2, pA3);
                pu.z = pk_bf16(pB0, pB1);
                pu.w = pk_bf16(pB2, pB3);
                const short8v pf8 = __builtin_bit_cast(short8v, pu);

                acc[f]  = mfma32(pf8, vt8,  acc[f]);    // O += P*V   (32 keys)
                accl[f] = mfma32(pf8, ones8, accl[f]);  // l += sum_k P
            }
        }

        if (c < NCH - 1) commit(smem[cur ^ 1]);  // convert+write after compute
        __syncthreads();
    }

    // epilogue: accl[f][r] == l for q-row 4g+r — no cross-lane traffic
    #pragma unroll
    for (int f = 0; f < 2; ++f) {
        const size_t obase = bh * SEQ + q0 + f * 64 + wave * 16;
        #pragma unroll
        for (int r = 0; r < 4; ++r) {
            out[(obase + 4 * g + r) * DK + n] = acc[f][r] / accl[f][r];
        }
    }
}

extern "C" void kernel_launch(void* const* d_in, const int* in_sizes, int n_in,
                              void* d_out, int out_size, void* d_ws, size_t ws_size,
                              hipStream_t stream) {
    (void)in_sizes; (void)n_in; (void)out_size; (void)d_ws; (void)ws_size;
    const float* Q    = (const float*)d_in[0];
    const float* K    = (const float*)d_in[1];
    const float* V    = (const float*)d_in[2];
    const int*   mask = (const int*)  d_in[3];
    const float* bias = (const float*)d_in[4];
    float* out = (float*)d_out;

    sdpa_fused<<<NBATCH * NHEAD * (SEQ / 128), 256, 0, stream>>>(Q, K, V, mask, bias, out);
}

// Round 6
// 201.267 us; speedup vs baseline: 1.2655x; 1.2655x over previous
//
#include <hip/hip_runtime.h>
#include <hip/hip_fp16.h>
#include <math.h>

#define SEQ    1024
#define DK     16
#define NHEAD  16
#define NBATCH 8
#define LOG2E  1.4426950408889634f
#define NEGBIG -60000.0f

#define CH     64                        // keys per LDS chunk
#define NCH    (SEQ / CH)                // 16 chunks
#define KHI_STRIDE 32                    // LDS bytes per key row (no pad; XOR swizzle)
#define VT_STRIDE  128                   // LDS bytes per d row   (no pad; XOR swizzle)
#define KHI_CH (CH * KHI_STRIDE)         // 2048 B
#define VT_CH  (DK * VT_STRIDE)         // 2048 B
#define BIAS_CH (128 * CH * 2)           // 16384 B (128 q-rows x 64 keys, fp16)
#define BUF_SZ (KHI_CH + VT_CH + BIAS_CH)// 20480 B per buffer (x2 = 40960 -> 4 blk/CU)

typedef __attribute__((ext_vector_type(4))) short  short4v;
typedef __attribute__((ext_vector_type(8))) short  short8v;
typedef __attribute__((ext_vector_type(2))) short  short2v;
typedef __attribute__((ext_vector_type(4))) float  float4v;
typedef __attribute__((ext_vector_type(2))) unsigned int uint2v;

static __device__ __forceinline__ float fast_exp2(float x) {
#if __has_builtin(__builtin_amdgcn_exp2f)
    return __builtin_amdgcn_exp2f(x);
#else
    return exp2f(x);
#endif
}

static __device__ __forceinline__ float4v mfma16(short4v a, short4v b, float4v c) {
#if __has_builtin(__builtin_amdgcn_mfma_f32_16x16x16bf16_1k)
    return __builtin_amdgcn_mfma_f32_16x16x16bf16_1k(a, b, c, 0, 0, 0);
#else
    float4v d = c;
    asm volatile("v_mfma_f32_16x16x16_bf16 %0, %1, %2, %0" : "+v"(d) : "v"(a), "v"(b));
    return d;
#endif
}

// K=32 MFMA: A/B = 8 bf16/lane (k = quad*8 + j). Fallback: two K=16 halves.
static __device__ __forceinline__ float4v mfma32(short8v a, short8v b, float4v c) {
#if __has_builtin(__builtin_amdgcn_mfma_f32_16x16x32_bf16)
    return __builtin_amdgcn_mfma_f32_16x16x32_bf16(a, b, c, 0, 0, 0);
#else
    short4v a0 = {a[0], a[1], a[2], a[3]}, a1 = {a[4], a[5], a[6], a[7]};
    short4v b0 = {b[0], b[1], b[2], b[3]}, b1 = {b[4], b[5], b[6], b[7]};
    c = mfma16(a0, b0, c);
    return mfma16(a1, b1, c);
#endif
}

static __device__ __forceinline__ unsigned bf16_rne(float x) {
    unsigned u = __float_as_uint(x);
    return (u + 0x7FFFu + ((u >> 16) & 1u)) >> 16;
}
static __device__ __forceinline__ float bf16_to_f(unsigned b) {
    return __uint_as_float(b << 16);
}
static __device__ __forceinline__ unsigned pk_bf16(float a, float b) {
#if __has_builtin(__builtin_amdgcn_cvt_pk_bf16_f32)
    short2v r = __builtin_amdgcn_cvt_pk_bf16_f32(a, b);
    return __builtin_bit_cast(unsigned, r);
#else
    return bf16_rne(a) | (bf16_rne(b) << 16);
#endif
}
static __device__ __forceinline__ short4v bc_s4(unsigned lo, unsigned hi) {
    uint2v u; u.x = lo; u.y = hi;
    return __builtin_bit_cast(short4v, u);
}

// ---------------- Fully fused flash pass -------------------------------------
// Round-6 = round-5 with ONE change: __launch_bounds__ min-waves 4 -> 3.
// Round-5 post-mortem: declaring 4 blocks/CU minimum forced the allocator to
// a 64-VGPR budget; the 48-VGPR staging pipeline (pb/pm) spilled to scratch
// (WRITE_SIZE 8 MB -> 105 MB, FETCH 52 -> 170 MB, dur 114 -> 164+ us).
// With min=3 the natural allocation is ~84 VGPR (round 4), which is <= 128,
// so 4 waves/SIMD — and the 40960 B LDS (round-5 win, kept) — still give
// 4 blocks/CU at runtime, now WITHOUT spills. Bias swizzle (round-5 win,
// kept): SQ_LDS_BANK_CONFLICT 9.2M -> 3.4M.
__global__ __launch_bounds__(256, 3)
void sdpa_fused(const float* __restrict__ Q, const float* __restrict__ K,
                const float* __restrict__ V, const int* __restrict__ mask,
                const float* __restrict__ bias, float* __restrict__ out) {
    __shared__ __align__(16) char smem[2][BUF_SZ];

    const int tid  = threadIdx.x;
    const int wave = tid >> 6;
    const int lane = tid & 63;
    const int n    = lane & 15;
    const int g    = lane >> 4;
    const int permn = ((n >> 2) << 3) | (n & 3);   // tile-pair key permutation
    const int lso  = (g * 16 + (n ^ g)) * 16;      // bias slot byte off (swizzled)

    const int b  = blockIdx.x & 7;                 // XCD = batch
    const int j  = blockIdx.x >> 3;                // 0..127
    const int h  = j & 15;                         // heads fastest (bias L2 share)
    const int qt = j >> 4;                         // 0..7
    const int q0 = qt * 128;
    const size_t bh = (size_t)b * NHEAD + h;

    // ---- Q fragments (hi/lo split; exact QK via 2 MFMAs) ----
    short4v qh[2], ql[2];
    #pragma unroll
    for (int f = 0; f < 2; ++f) {
        const int qrow = q0 + f * 64 + wave * 16 + n;
        const float4 qv = *(const float4*)(Q + (bh * SEQ + qrow) * DK + g * 4);
        const float qsc = 0.25f * LOG2E;
        const float v[4] = {qv.x * qsc, qv.y * qsc, qv.z * qsc, qv.w * qsc};
        #pragma unroll
        for (int e = 0; e < 4; ++e) {
            const unsigned hu = bf16_rne(v[e]);
            qh[f][e] = (short)hu;
            ql[f][e] = (short)bf16_rne(v[e] - bf16_to_f(hu));
        }
    }

    const float* Kb = K + bh * SEQ * DK;
    const float* Vb = V + bh * SEQ * DK;

    // K/V staging roles (wave-uniform split):
    const int skey = tid >> 1, shh = tid & 1;                 // tid < 128 : K
    const int sk2  = (tid - 128) >> 2, sdq = (tid - 128) & 3; // tid >= 128 : V

    // bias stager coords: thread -> (row group brow, key-quad kq4)
    const int brow = tid >> 4;                 // 0..15
    const int kq4  = tid & 15;                 // float4 index in 64-key chunk
    const int tpo  = kq4 >> 3;                 // tile-pair
    const int g_s  = (kq4 >> 1) & 3;           // key-octet
    const int half_s = kq4 & 1;                // low/high 4 keys of octet
    const int up   = g_s * 16 + (brow ^ g_s);  // swizzled 16B slot (matches lso)
    const int boff = up * 16 + half_s * 8;
    const float* bRow0 = bias + (size_t)b * SEQ * SEQ + (size_t)(q0 + brow) * SEQ + kq4 * 4;
    const int*   mRow0 = mask + (size_t)b * SEQ * SEQ + (size_t)(q0 + brow) * SEQ + kq4 * 4;

    float4v acc[2], accl[2];
    acc[0]  = (float4v){0.f, 0.f, 0.f, 0.f};
    acc[1]  = (float4v){0.f, 0.f, 0.f, 0.f};
    accl[0] = (float4v){0.f, 0.f, 0.f, 0.f};
    accl[1] = (float4v){0.f, 0.f, 0.f, 0.f};
    const short8v ones8 = {(short)0x3F80, (short)0x3F80, (short)0x3F80, (short)0x3F80,
                           (short)0x3F80, (short)0x3F80, (short)0x3F80, (short)0x3F80};

    float4 pb[8]; int4 pm[8];                  // in-flight bias/mask (8 passes)
    float4 kv0, kv1;                           // in-flight K or V

    auto issue = [&](int kc) {
        #pragma unroll
        for (int p = 0; p < 8; ++p) {
            pb[p] = *(const float4*)(bRow0 + (size_t)p * 16 * SEQ + kc);
            pm[p] = *(const int4*)  (mRow0 + (size_t)p * 16 * SEQ + kc);
        }
        if (tid < 128) {
            kv0 = *(const float4*)(Kb + (kc + skey) * DK + shh * 8);
            kv1 = *(const float4*)(Kb + (kc + skey) * DK + shh * 8 + 4);
        } else {
            kv0 = *(const float4*)(Vb + (kc + 2 * sk2) * DK + sdq * 4);
            kv1 = *(const float4*)(Vb + (kc + 2 * sk2 + 1) * DK + sdq * 4);
        }
    };

    auto commit = [&](char* s) {
        if (tid < 128) {
            uint4 kp;
            kp.x = pk_bf16(kv0.x, kv0.y); kp.y = pk_bf16(kv0.z, kv0.w);
            kp.z = pk_bf16(kv1.x, kv1.y); kp.w = pk_bf16(kv1.z, kv1.w);
            // physical(row,hh) = row*32 + (hh ^ ((row>>3)&1))*16
            *(uint4*)(s + skey * KHI_STRIDE + ((shh ^ ((skey >> 3) & 1)) * 16)) = kp;
        } else {
            char* sv = s + KHI_CH;
            const float* pa = (const float*)&kv0;
            const float* pv = (const float*)&kv1;
            #pragma unroll
            for (int jj = 0; jj < 4; ++jj) {
                const int row = 4 * sdq + jj;
                // physical octet = (sk2>>2) ^ (row&7)
                *(unsigned*)(sv + row * VT_STRIDE +
                             (((sk2 >> 2) ^ (row & 7)) * 16) + (sk2 & 3) * 4) =
                    pk_bf16(pa[jj], pv[jj]);
            }
        }
        char* bs = s + KHI_CH + VT_CH;
        #pragma unroll
        for (int p = 0; p < 8; ++p) {
            const float4 bv = pb[p]; const int4 mv = pm[p];
            const __half2 lo = __floats2half2_rn(mv.x ? NEGBIG : bv.x * LOG2E,
                                                 mv.y ? NEGBIG : bv.y * LOG2E);
            const __half2 hi = __floats2half2_rn(mv.z ? NEGBIG : bv.z * LOG2E,
                                                 mv.w ? NEGBIG : bv.w * LOG2E);
            uint2 u;
            u.x = __builtin_bit_cast(unsigned, lo);
            u.y = __builtin_bit_cast(unsigned, hi);
            // block index (f*2+tp)*4 + w  ->  f = p>>2, w = p&3
            *(uint2*)(bs + ((p >> 2) * 2 + tpo) * 4096 + (p & 3) * 1024 + boff) = u;
        }
    };

    // prologue: stage chunk 0
    issue(0);
    commit(smem[0]);
    __syncthreads();

    for (int c = 0; c < NCH; ++c) {
        const int cur = c & 1;
        if (c < NCH - 1) issue((c + 1) * CH);   // chunk-distance prefetch
#if __has_builtin(__builtin_amdgcn_sched_barrier)
        __builtin_amdgcn_sched_barrier(0);      // pin loads above compute
#endif
        const char* khl = smem[cur];
        const char* vtl = smem[cur] + KHI_CH;
        const char* bsl = smem[cur] + KHI_CH + VT_CH;

        #pragma unroll
        for (int tp = 0; tp < 2; ++tp) {
            const int rowA = tp * 32 + permn;
            const int rowB = rowA + 4;
            const int swA = (rowA >> 3) & 1;
            const int swB = (rowB >> 3) & 1;
            const uint2 kAu = *(const uint2*)(khl + rowA * KHI_STRIDE +
                                              (((g >> 1) ^ swA) * 16) + (g & 1) * 8);
            const uint2 kBu = *(const uint2*)(khl + rowB * KHI_STRIDE +
                                              (((g >> 1) ^ swB) * 16) + (g & 1) * 8);
            const uint4 vv  = *(const uint4*)(vtl + n * VT_STRIDE +
                                              (((tp * 4 + g) ^ (n & 7)) * 16));
            const short4v khiA = bc_s4(kAu.x, kAu.y);
            const short4v khiB = bc_s4(kBu.x, kBu.y);
            const short8v vt8  = __builtin_bit_cast(short8v, vv);

            #pragma unroll
            for (int f = 0; f < 2; ++f) {
                const uint4 bb = *(const uint4*)(bsl + ((f * 2 + tp) * 4 + wave) * 1024 + lso);
                const float2 a01 = __half22float2(__builtin_bit_cast(__half2, bb.x));
                const float2 a23 = __half22float2(__builtin_bit_cast(__half2, bb.y));
                float4v sA; sA[0] = a01.x; sA[1] = a01.y; sA[2] = a23.x; sA[3] = a23.y;
                sA = mfma16(khiA, qh[f], sA);
                sA = mfma16(khiA, ql[f], sA);
                const float2 b01 = __half22float2(__builtin_bit_cast(__half2, bb.z));
                const float2 b23 = __half22float2(__builtin_bit_cast(__half2, bb.w));
                float4v sB; sB[0] = b01.x; sB[1] = b01.y; sB[2] = b23.x; sB[3] = b23.y;
                sB = mfma16(khiB, qh[f], sB);
                sB = mfma16(khiB, ql[f], sB);

                const float pA0 = fast_exp2(sA[0]), pA1 = fast_exp2(sA[1]);
                const float pA2 = fast_exp2(sA[2]), pA3 = fast_exp2(sA[3]);
                const float pB0 = fast_exp2(sB[0]), pB1 = fast_exp2(sB[1]);
                const float pB2 = fast_exp2(sB[2]), pB3 = fast_exp2(sB[3]);

                // K=32 A-frag: [pA0..3, pB0..3] == keys 8g..8g+7 (k = quad*8+j)
                uint4 pu;
                pu.x = pk_bf16(pA0, pA1);
                pu.y = pk_bf16(pA2, pA3);
                pu.z = pk_bf16(pB0, pB1);
                pu.w = pk_bf16(pB2, pB3);
                const short8v pf8 = __builtin_bit_cast(short8v, pu);

                acc[f]  = mfma32(pf8, vt8,  acc[f]);    // O += P*V   (32 keys)
                accl[f] = mfma32(pf8, ones8, accl[f]);  // l += sum_k P
            }
        }

        if (c < NCH - 1) commit(smem[cur ^ 1]);  // convert+write after compute
        __syncthreads();
    }

    // epilogue: accl[f][r] == l for q-row 4g+r — no cross-lane traffic
    #pragma unroll
    for (int f = 0; f < 2; ++f) {
        const size_t obase = bh * SEQ + q0 + f * 64 + wave * 16;
        #pragma unroll
        for (int r = 0; r < 4; ++r) {
            out[(obase + 4 * g + r) * DK + n] = acc[f][r] / accl[f][r];
        }
    }
}

extern "C" void kernel_launch(void* const* d_in, const int* in_sizes, int n_in,
                              void* d_out, int out_size, void* d_ws, size_t ws_size,
                              hipStream_t stream) {
    (void)in_sizes; (void)n_in; (void)out_size; (void)d_ws; (void)ws_size;
    const float* Q    = (const float*)d_in[0];
    const float* K    = (const float*)d_in[1];
    const float* V    = (const float*)d_in[2];
    const int*   mask = (const int*)  d_in[3];
    const float* bias = (const float*)d_in[4];
    float* out = (float*)d_out;

    sdpa_fused<<<NBATCH * NHEAD * (SEQ / 128), 256, 0, stream>>>(Q, K, V, mask, bias, out);
}

// Round 7
// 165.393 us; speedup vs baseline: 1.5399x; 1.2169x over previous
//
#include <hip/hip_runtime.h>
#include <hip/hip_fp16.h>
#include <math.h>

#define SEQ    1024
#define DK     16
#define NHEAD  16
#define NBATCH 8
#define LOG2E  1.4426950408889634f

#define CH     128                       // keys per LDS chunk
#define NCH    (SEQ / CH)                // 8 chunks
#define KHI_STRIDE 40                    // LDS bytes per key row (32 data + 8 pad)
#define VT_STRIDE  272                   // LDS bytes per d row   (256 data + 16 pad)
#define KHI_CH (CH * KHI_STRIDE)         // 5120 B
#define VT_CH  (DK * VT_STRIDE)          // 4352 B
#define BUF_SZ (KHI_CH + VT_CH)          // 9472 B per buffer (x2 = 18.9 KB)

typedef __attribute__((ext_vector_type(4))) short  short4v;
typedef __attribute__((ext_vector_type(8))) short  short8v;
typedef __attribute__((ext_vector_type(2))) short  short2v;
typedef __attribute__((ext_vector_type(4))) float  float4v;
typedef __attribute__((ext_vector_type(2))) unsigned int uint2v;

static __device__ __forceinline__ float fast_exp2(float x) {
#if __has_builtin(__builtin_amdgcn_exp2f)
    return __builtin_amdgcn_exp2f(x);
#else
    return exp2f(x);
#endif
}

static __device__ __forceinline__ float4v mfma16(short4v a, short4v b, float4v c) {
#if __has_builtin(__builtin_amdgcn_mfma_f32_16x16x16bf16_1k)
    return __builtin_amdgcn_mfma_f32_16x16x16bf16_1k(a, b, c, 0, 0, 0);
#else
    float4v d = c;
    asm volatile("v_mfma_f32_16x16x16_bf16 %0, %1, %2, %0" : "+v"(d) : "v"(a), "v"(b));
    return d;
#endif
}

// K=32 MFMA: A/B = 8 bf16/lane (k = quad*8 + j). Fallback: two K=16 halves.
static __device__ __forceinline__ float4v mfma32(short8v a, short8v b, float4v c) {
#if __has_builtin(__builtin_amdgcn_mfma_f32_16x16x32_bf16)
    return __builtin_amdgcn_mfma_f32_16x16x32_bf16(a, b, c, 0, 0, 0);
#else
    short4v a0 = {a[0], a[1], a[2], a[3]}, a1 = {a[4], a[5], a[6], a[7]};
    short4v b0 = {b[0], b[1], b[2], b[3]}, b1 = {b[4], b[5], b[6], b[7]};
    c = mfma16(a0, b0, c);
    return mfma16(a1, b1, c);
#endif
}

static __device__ __forceinline__ unsigned bf16_rne(float x) {
    unsigned u = __float_as_uint(x);
    return (u + 0x7FFFu + ((u >> 16) & 1u)) >> 16;
}
static __device__ __forceinline__ float bf16_to_f(unsigned b) {
    return __uint_as_float(b << 16);
}
static __device__ __forceinline__ unsigned pk_bf16(float a, float b) {
#if __has_builtin(__builtin_amdgcn_cvt_pk_bf16_f32)
    short2v r = __builtin_amdgcn_cvt_pk_bf16_f32(a, b);
    return __builtin_bit_cast(unsigned, r);
#else
    return bf16_rne(a) | (bf16_rne(b) << 16);
#endif
}
static __device__ __forceinline__ short4v bc_s4(unsigned lo, unsigned hi) {
    uint2v u; u.x = lo; u.y = hi;
    return __builtin_bit_cast(short4v, u);
}
static __device__ __forceinline__ unsigned h2pack(int m0, float b0, int m1, float b1) {
    const __half2 a = __floats2half2_rn(m0 ? -60000.f : b0 * LOG2E,
                                        m1 ? -60000.f : b1 * LOG2E);
    return __builtin_bit_cast(unsigned, a);
}

// ---------------- Prep (one kernel, 3 jobs by block range) -------------------
// [0,2048):     bias+mask -> biasp fp16 fragment-major (64q x 64k per block)
// [2048,2560):  K -> Khi bf16 (plain rounding, 32 B per key row)
// [2560,3072):  V -> Vt bf16 [B*H][d][s]
__global__ __launch_bounds__(256)
void prep_all(const float* __restrict__ K, const float* __restrict__ V,
              const int* __restrict__ mask, const float* __restrict__ bias,
              uint2* __restrict__ KHI, short* __restrict__ Vt,
              uint4* __restrict__ biasp) {
    const int blk = blockIdx.x;
    const int t   = threadIdx.x;
    if (blk < 2048) {
        __shared__ uint4 BsT[64][9];
        const int b    = blk >> 8;
        const int qt64 = (blk >> 4) & 15;
        const int c    = (blk >> 1) & 7;
        const int half = blk & 1;
        const int kb   = c * 128 + half * 64;
        #pragma unroll
        for (int i = 0; i < 4; ++i) {
            const int idx = t + i * 256;                 // 0..1023
            const int row = idx >> 4;                    // q-local 0..63
            const int c4  = idx & 15;                    // float4 col in 64-k window
            const size_t ga = ((size_t)b * SEQ + qt64 * 64 + row) * SEQ + kb + c4 * 4;
            const float4 bv = *(const float4*)(bias + ga);
            const int4   mv = *(const int4*)(mask + ga);
            uint2 u;
            u.x = h2pack(mv.x, bv.x, mv.y, bv.y);
            u.y = h2pack(mv.z, bv.z, mv.w, bv.w);
            const int jj = c4 >> 1;
            ((uint2*)&BsT[row][jj ^ (row & 7)])[c4 & 1] = u;
        }
        __syncthreads();
        const int w = t >> 6, lane = t & 63, n = lane & 15, g = lane >> 4;
        const int row = w * 16 + n;
        #pragma unroll
        for (int tpl = 0; tpl < 2; ++tpl) {
            const int tp = half * 2 + tpl;
            const int jj = tpl * 4 + g;
            const uint4 v = BsT[row][jj ^ (row & 7)];
            const size_t ob = ((((size_t)(b * 16 + qt64) * 4 + w) * 8 + c) * 4 + tp) * 64 + lane;
            biasp[ob] = v;
        }
    } else if (blk < 2560) {
        const int base = (blk - 2048) * 1024;
        #pragma unroll
        for (int i = 0; i < 4; ++i) {
            const int i4 = base + t + i * 256;           // float4 index into K
            const float4 k = ((const float4*)K)[i4];
            uint2 o;
            o.x = pk_bf16(k.x, k.y);
            o.y = pk_bf16(k.z, k.w);
            KHI[i4] = o;
        }
    } else {
        __shared__ float Vs[64][17];
        const int vb = blk - 2560;                       // 0..511
        const int bh = vb >> 2;
        const int qq = vb & 3;
        #pragma unroll
        for (int st = 0; st < 4; ++st) {
            const int s0 = qq * 256 + st * 64;
            {
                const int row = t >> 2, c4 = t & 3;
                const float4 v = ((const float4*)V)[((size_t)bh * SEQ + s0 + row) * 4 + c4];
                Vs[row][c4 * 4 + 0] = v.x; Vs[row][c4 * 4 + 1] = v.y;
                Vs[row][c4 * 4 + 2] = v.z; Vs[row][c4 * 4 + 3] = v.w;
            }
            __syncthreads();
            const int d = t >> 4, sg = t & 15;
            short4v o;
            #pragma unroll
            for (int i = 0; i < 4; ++i) o[i] = (short)bf16_rne(Vs[sg * 4 + i][d]);
            ((short4v*)Vt)[(((size_t)bh * DK + d) * SEQ + s0) / 4 + sg] = o;
            __syncthreads();
        }
    }
}

// ---------------- Flash pass ------------------------------------------------
// Round-7: two-kernel design restored (fused variant has a ~31 us/XCD L2 floor
// from 16x bias re-read + duplicated conversion; measured 114 us vs 70 us
// on-GPU for this split). ONE change vs the verified 43-us flash: q-tile
// 128 -> 64 rows (1 frag/wave), grid 1024 -> 2048 = 8 blocks/CU (LDS
// 8 x 18.9 KB = 151.5 KB fits) to double TLP — round-0 showed occupancy 30%
// with latency-shaped stalls (VALUBusy 56, MfmaUtil 23, HBM 7%).
// biasp is already tiled per 64 q-rows, so this is an index-only change.
__global__ __launch_bounds__(256, 8)
void sdpa_flash(const float* __restrict__ Q, const uint2* __restrict__ KHI,
                const short* __restrict__ Vt, const uint4* __restrict__ biasp,
                float* __restrict__ out) {
    __shared__ __align__(16) char smem[2][BUF_SZ];

    const int tid  = threadIdx.x;
    const int wave = tid >> 6;
    const int lane = tid & 63;
    const int n    = lane & 15;
    const int g    = lane >> 4;
    const int permn = ((n >> 2) << 3) | (n & 3);   // tile-pair key permutation

    const int b    = blockIdx.x & 7;               // XCD = batch
    const int j    = blockIdx.x >> 3;              // 0..255
    const int qt64 = j & 15;                       // 64-row q tile (qt fastest)
    const int h    = j >> 4;                       // 0..15
    const int q0   = qt64 * 64;

    const size_t bh = (size_t)b * NHEAD + h;

    // 1 q-frag: q = q0 + wave*16 + n
    short4v qh, ql;
    {
        const int qrow = q0 + wave * 16 + n;
        const float4 qv = *(const float4*)(Q + (bh * SEQ + qrow) * DK + g * 4);
        const float qsc = 0.25f * LOG2E;
        const float v[4] = {qv.x * qsc, qv.y * qsc, qv.z * qsc, qv.w * qsc};
        #pragma unroll
        for (int e = 0; e < 4; ++e) {
            const unsigned hu = bf16_rne(v[e]);
            qh[e] = (short)hu;
            ql[e] = (short)bf16_rne(v[e] - bf16_to_f(hu));
        }
    }
    const size_t bfbase = (((size_t)(b * 16 + qt64) * 4 + wave) * 32) * 64 + lane;

    const uint4* KHIh = (const uint4*)(KHI + bh * SEQ * 4); // 2 uint4 per key row
    const uint4* VtH  = (const uint4*)(Vt + bh * DK * SEQ);

    float4v acc, accl;
    acc  = (float4v){0.f, 0.f, 0.f, 0.f};
    accl = (float4v){0.f, 0.f, 0.f, 0.f};
    const short8v ones8 = {(short)0x3F80, (short)0x3F80, (short)0x3F80, (short)0x3F80,
                           (short)0x3F80, (short)0x3F80, (short)0x3F80, (short)0x3F80};

    // staging: K chunk = 256 uint4 (key = e>>1, half-row = e&1); V = 256 uint4
    uint4 st0, st2;
    {
        st0 = KHIh[tid];
        st2 = VtH[(tid >> 4) * 128 + (tid & 15)];
        char* s = smem[0];
        *(uint4*)(s + (tid >> 1) * KHI_STRIDE + (tid & 1) * 16) = st0;
        *(uint4*)(s + KHI_CH + (tid >> 4) * VT_STRIDE + (tid & 15) * 16) = st2;
    }
    __syncthreads();

    for (int c = 0; c < NCH; ++c) {
        const int cur = c & 1;
        if (c < NCH - 1) {
            st0 = KHIh[(c + 1) * 256 + tid];
            st2 = VtH[(tid >> 4) * 128 + (c + 1) * 16 + (tid & 15)];
        }
        uint4 bb[4];
        #pragma unroll
        for (int tp = 0; tp < 4; ++tp)
            bb[tp] = biasp[bfbase + (size_t)(c * 4 + tp) * 64];

        const char* khl = smem[cur];
        const char* vtl = smem[cur] + KHI_CH;

        #pragma unroll
        for (int tp = 0; tp < 4; ++tp) {
            const int rowA = tp * 32 + permn;
            const uint2 kAu = *(const uint2*)(khl + rowA * KHI_STRIDE + g * 8);
            const uint2 kBu = *(const uint2*)(khl + (rowA + 4) * KHI_STRIDE + g * 8);
            const uint4 vv  = *(const uint4*)(vtl + n * VT_STRIDE + tp * 64 + g * 16);
            const short4v khiA = bc_s4(kAu.x, kAu.y);
            const short4v khiB = bc_s4(kBu.x, kBu.y);
            const short8v vt8  = __builtin_bit_cast(short8v, vv);

            // tile A scores: keys c*128 + tp*32 + 8g + r
            const float2 a01 = __half22float2(__builtin_bit_cast(__half2, bb[tp].x));
            const float2 a23 = __half22float2(__builtin_bit_cast(__half2, bb[tp].y));
            float4v sA; sA[0] = a01.x; sA[1] = a01.y; sA[2] = a23.x; sA[3] = a23.y;
            sA = mfma16(khiA, qh, sA);
            sA = mfma16(khiA, ql, sA);
            // tile B scores: keys c*128 + tp*32 + 8g + 4 + r
            const float2 b01 = __half22float2(__builtin_bit_cast(__half2, bb[tp].z));
            const float2 b23 = __half22float2(__builtin_bit_cast(__half2, bb[tp].w));
            float4v sB; sB[0] = b01.x; sB[1] = b01.y; sB[2] = b23.x; sB[3] = b23.y;
            sB = mfma16(khiB, qh, sB);
            sB = mfma16(khiB, ql, sB);

            const float pA0 = fast_exp2(sA[0]), pA1 = fast_exp2(sA[1]);
            const float pA2 = fast_exp2(sA[2]), pA3 = fast_exp2(sA[3]);
            const float pB0 = fast_exp2(sB[0]), pB1 = fast_exp2(sB[1]);
            const float pB2 = fast_exp2(sB[2]), pB3 = fast_exp2(sB[3]);

            // K=32 A-frag: [pA0..3, pB0..3] == keys 8g..8g+7 (k = quad*8+j)
            uint4 pu;
            pu.x = pk_bf16(pA0, pA1);
            pu.y = pk_bf16(pA2, pA3);
            pu.z = pk_bf16(pB0, pB1);
            pu.w = pk_bf16(pB2, pB3);
            const short8v pf8 = __builtin_bit_cast(short8v, pu);

            acc  = mfma32(pf8, vt8,  acc);     // O += P*V   (32 keys)
            accl = mfma32(pf8, ones8, accl);   // l += sum_k P
        }

        if (c < NCH - 1) {
            char* s = smem[cur ^ 1];
            *(uint4*)(s + (tid >> 1) * KHI_STRIDE + (tid & 1) * 16) = st0;
            *(uint4*)(s + KHI_CH + (tid >> 4) * VT_STRIDE + (tid & 15) * 16) = st2;
        }
        __syncthreads();
    }

    // epilogue: accl[r] == l for q-row 4g+r — no cross-lane traffic
    {
        const size_t obase = bh * SEQ + q0 + wave * 16;
        #pragma unroll
        for (int r = 0; r < 4; ++r) {
            out[(obase + 4 * g + r) * DK + n] = acc[r] / accl[r];
        }
    }
}

// ---------------- Fallback: single-pass scalar kernel (no workspace) ---------
#define FTQ 256
#define FTK 32
__global__ __launch_bounds__(256, 2)
void sdpa_fallback(const float* __restrict__ Q, const float* __restrict__ K,
                   const float* __restrict__ V, const int* __restrict__ mask,
                   const float* __restrict__ bias, float* __restrict__ out) {
    __shared__ float Ks[FTK][DK];
    __shared__ float Vs[FTK][DK];
    __shared__ float Bsf[FTQ][FTK + 1];

    const int tid = threadIdx.x;
    const int blk = blockIdx.x;
    const int h   = blk & (NHEAD - 1);
    const int qt  = (blk >> 4) & 3;
    const int b   = blk >> 6;
    const int q0  = qt * FTQ;
    const float qscale = 0.25f * LOG2E;
    const size_t bh = (size_t)b * NHEAD + h;

    float Qr[DK];
    {
        const float4* q4 = (const float4*)(Q + (bh * SEQ + q0 + tid) * DK);
        #pragma unroll
        for (int i = 0; i < 4; ++i) {
            float4 v = q4[i];
            Qr[4*i+0] = v.x * qscale; Qr[4*i+1] = v.y * qscale;
            Qr[4*i+2] = v.z * qscale; Qr[4*i+3] = v.w * qscale;
        }
    }
    float acc[DK];
    #pragma unroll
    for (int d = 0; d < DK; ++d) acc[d] = 0.0f;
    float l = 0.0f;

    const float* Kbase = K + bh * SEQ * DK;
    const float* Vbase = V + bh * SEQ * DK;
    const float* Bbase = bias + ((size_t)b * SEQ + q0) * SEQ;
    const int*   Mbase = mask + ((size_t)b * SEQ + q0) * SEQ;

    for (int t = 0; t < SEQ / FTK; ++t) {
        const int k0 = t * FTK;
        if (tid < 128) {
            float4 kv = ((const float4*)(Kbase + (size_t)k0 * DK))[tid];
            float4 vv = ((const float4*)(Vbase + (size_t)k0 * DK))[tid];
            ((float4*)&Ks[0][0])[tid] = kv;
            ((float4*)&Vs[0][0])[tid] = vv;
        }
        #pragma unroll
        for (int i = 0; i < 8; ++i) {
            int e4 = tid + i * 256, row = e4 >> 3, c4 = e4 & 7;
            const float4 bv = *(const float4*)(Bbase + (size_t)row * SEQ + k0 + c4 * 4);
            const int4   mv = *(const int4*)  (Mbase + (size_t)row * SEQ + k0 + c4 * 4);
            float* dst = &Bsf[row][c4 * 4];
            dst[0] = mv.x ? -1e9f : bv.x * LOG2E;
            dst[1] = mv.y ? -1e9f : bv.y * LOG2E;
            dst[2] = mv.z ? -1e9f : bv.z * LOG2E;
            dst[3] = mv.w ? -1e9f : bv.w * LOG2E;
        }
        __syncthreads();
        #pragma unroll 4
        for (int kk = 0; kk < FTK; ++kk) {
            float s = Bsf[tid][kk];
            const float4 k0v = *(const float4*)&Ks[kk][0];
            const float4 k1v = *(const float4*)&Ks[kk][4];
            const float4 k2v = *(const float4*)&Ks[kk][8];
            const float4 k3v = *(const float4*)&Ks[kk][12];
            s = fmaf(Qr[0],  k0v.x, s); s = fmaf(Qr[1],  k0v.y, s);
            s = fmaf(Qr[2],  k0v.z, s); s = fmaf(Qr[3],  k0v.w, s);
            s = fmaf(Qr[4],  k1v.x, s); s = fmaf(Qr[5],  k1v.y, s);
            s = fmaf(Qr[6],  k1v.z, s); s = fmaf(Qr[7],  k1v.w, s);
            s = fmaf(Qr[8],  k2v.x, s); s = fmaf(Qr[9],  k2v.y, s);
            s = fmaf(Qr[10], k2v.z, s); s = fmaf(Qr[11], k2v.w, s);
            s = fmaf(Qr[12], k3v.x, s); s = fmaf(Qr[13], k3v.y, s);
            s = fmaf(Qr[14], k3v.z, s); s = fmaf(Qr[15], k3v.w, s);
            float p = fast_exp2(s);
            l += p;
            const float4 v0 = *(const float4*)&Vs[kk][0];
            const float4 v1 = *(const float4*)&Vs[kk][4];
            const float4 v2 = *(const float4*)&Vs[kk][8];
            const float4 v3 = *(const float4*)&Vs[kk][12];
            acc[0]  = fmaf(p, v0.x, acc[0]);  acc[1]  = fmaf(p, v0.y, acc[1]);
            acc[2]  = fmaf(p, v0.z, acc[2]);  acc[3]  = fmaf(p, v0.w, acc[3]);
            acc[4]  = fmaf(p, v1.x, acc[4]);  acc[5]  = fmaf(p, v1.y, acc[5]);
            acc[6]  = fmaf(p, v1.z, acc[6]);  acc[7]  = fmaf(p, v1.w, acc[7]);
            acc[8]  = fmaf(p, v2.x, acc[8]);  acc[9]  = fmaf(p, v2.y, acc[9]);
            acc[10] = fmaf(p, v2.z, acc[10]); acc[11] = fmaf(p, v2.w, acc[11]);
            acc[12] = fmaf(p, v3.x, acc[12]); acc[13] = fmaf(p, v3.y, acc[13]);
            acc[14] = fmaf(p, v3.z, acc[14]); acc[15] = fmaf(p, v3.w, acc[15]);
        }
        __syncthreads();
    }
    const float inv = 1.0f / l;
    float4* o4 = (float4*)(out + (bh * SEQ + q0 + tid) * DK);
    #pragma unroll
    for (int i = 0; i < 4; ++i) {
        float4 v;
        v.x = acc[4*i+0] * inv; v.y = acc[4*i+1] * inv;
        v.z = acc[4*i+2] * inv; v.w = acc[4*i+3] * inv;
        o4[i] = v;
    }
}

extern "C" void kernel_launch(void* const* d_in, const int* in_sizes, int n_in,
                              void* d_out, int out_size, void* d_ws, size_t ws_size,
                              hipStream_t stream) {
    const float* Q    = (const float*)d_in[0];
    const float* K    = (const float*)d_in[1];
    const float* V    = (const float*)d_in[2];
    const int*   mask = (const int*)  d_in[3];
    const float* bias = (const float*)d_in[4];
    float* out = (float*)d_out;

    const size_t nKeys    = (size_t)NBATCH * NHEAD * SEQ;      // 131072
    const size_t khiBytes = nKeys * 32;                        // 4.19 MB
    const size_t vtBytes  = nKeys * DK * sizeof(short);        // 4.19 MB
    const size_t bpBytes  = (size_t)NBATCH * SEQ * SEQ * 2;    // 16.8 MB
    const size_t need     = khiBytes + vtBytes + bpBytes;      // 25.2 MB

    if (ws_size >= need) {
        char* w = (char*)d_ws;
        uint2* KHI   = (uint2*)(w);
        short* Vt    = (short*)(w + khiBytes);
        uint4* biasp = (uint4*)(w + khiBytes + vtBytes);

        prep_all<<<3072, 256, 0, stream>>>(K, V, mask, bias, KHI, Vt, biasp);
        sdpa_flash<<<NBATCH * NHEAD * (SEQ / 64), 256, 0, stream>>>(Q, KHI, Vt, biasp, out);
    } else {
        sdpa_fallback<<<NBATCH * NHEAD * (SEQ / FTQ), FTQ, 0, stream>>>(Q, K, V, mask, bias, out);
    }
}

// Round 8
// 163.724 us; speedup vs baseline: 1.5556x; 1.0102x over previous
//
#include <hip/hip_runtime.h>
#include <hip/hip_fp16.h>
#include <math.h>

#define SEQ    1024
#define DK     16
#define NHEAD  16
#define NBATCH 8
#define LOG2E  1.4426950408889634f

#define CH     128                       // keys per LDS chunk
#define NCH    (SEQ / CH)                // 8 chunks
#define KHI_STRIDE 40                    // LDS bytes per key row (32 data + 8 pad)
#define VT_STRIDE  272                   // LDS bytes per d row   (256 data + 16 pad)
#define KHI_CH (CH * KHI_STRIDE)         // 5120 B
#define VT_CH  (DK * VT_STRIDE)          // 4352 B
#define BUF_SZ (KHI_CH + VT_CH)          // 9472 B per buffer (x2 = 18.9 KB)

typedef __attribute__((ext_vector_type(4))) short  short4v;
typedef __attribute__((ext_vector_type(8))) short  short8v;
typedef __attribute__((ext_vector_type(2))) short  short2v;
typedef __attribute__((ext_vector_type(4))) float  float4v;
typedef __attribute__((ext_vector_type(2))) unsigned int uint2v;

static __device__ __forceinline__ float fast_exp2(float x) {
#if __has_builtin(__builtin_amdgcn_exp2f)
    return __builtin_amdgcn_exp2f(x);
#else
    return exp2f(x);
#endif
}

static __device__ __forceinline__ float4v mfma16(short4v a, short4v b, float4v c) {
#if __has_builtin(__builtin_amdgcn_mfma_f32_16x16x16bf16_1k)
    return __builtin_amdgcn_mfma_f32_16x16x16bf16_1k(a, b, c, 0, 0, 0);
#else
    float4v d = c;
    asm volatile("v_mfma_f32_16x16x16_bf16 %0, %1, %2, %0" : "+v"(d) : "v"(a), "v"(b));
    return d;
#endif
}

// K=32 MFMA: A/B = 8 bf16/lane (k = quad*8 + j). Fallback: two K=16 halves.
static __device__ __forceinline__ float4v mfma32(short8v a, short8v b, float4v c) {
#if __has_builtin(__builtin_amdgcn_mfma_f32_16x16x32_bf16)
    return __builtin_amdgcn_mfma_f32_16x16x32_bf16(a, b, c, 0, 0, 0);
#else
    short4v a0 = {a[0], a[1], a[2], a[3]}, a1 = {a[4], a[5], a[6], a[7]};
    short4v b0 = {b[0], b[1], b[2], b[3]}, b1 = {b[4], b[5], b[6], b[7]};
    c = mfma16(a0, b0, c);
    return mfma16(a1, b1, c);
#endif
}

static __device__ __forceinline__ unsigned bf16_rne(float x) {
    unsigned u = __float_as_uint(x);
    return (u + 0x7FFFu + ((u >> 16) & 1u)) >> 16;
}
static __device__ __forceinline__ float bf16_to_f(unsigned b) {
    return __uint_as_float(b << 16);
}
static __device__ __forceinline__ unsigned pk_bf16(float a, float b) {
#if __has_builtin(__builtin_amdgcn_cvt_pk_bf16_f32)
    short2v r = __builtin_amdgcn_cvt_pk_bf16_f32(a, b);
    return __builtin_bit_cast(unsigned, r);
#else
    return bf16_rne(a) | (bf16_rne(b) << 16);
#endif
}
static __device__ __forceinline__ unsigned h2pack(int m0, float b0, int m1, float b1) {
    const __half2 a = __floats2half2_rn(m0 ? -60000.f : b0 * LOG2E,
                                        m1 ? -60000.f : b1 * LOG2E);
    return __builtin_bit_cast(unsigned, a);
}

// ---------------- Prep (one kernel, 3 jobs by block range) -------------------
// [0,2048):     bias+mask -> biasp fp16 fragment-major (64q x 64k per block)
// [2048,2560):  K -> Khi bf16 (plain rounding, 32 B per key row)
// [2560,3072):  V -> Vt bf16 [B*H][d][s]
__global__ __launch_bounds__(256)
void prep_all(const float* __restrict__ K, const float* __restrict__ V,
              const int* __restrict__ mask, const float* __restrict__ bias,
              uint2* __restrict__ KHI, short* __restrict__ Vt,
              uint4* __restrict__ biasp) {
    const int blk = blockIdx.x;
    const int t   = threadIdx.x;
    if (blk < 2048) {
        __shared__ uint4 BsT[64][9];
        const int b    = blk >> 8;
        const int qt64 = (blk >> 4) & 15;
        const int c    = (blk >> 1) & 7;
        const int half = blk & 1;
        const int kb   = c * 128 + half * 64;
        #pragma unroll
        for (int i = 0; i < 4; ++i) {
            const int idx = t + i * 256;                 // 0..1023
            const int row = idx >> 4;                    // q-local 0..63
            const int c4  = idx & 15;                    // float4 col in 64-k window
            const size_t ga = ((size_t)b * SEQ + qt64 * 64 + row) * SEQ + kb + c4 * 4;
            const float4 bv = *(const float4*)(bias + ga);
            const int4   mv = *(const int4*)(mask + ga);
            uint2 u;
            u.x = h2pack(mv.x, bv.x, mv.y, bv.y);
            u.y = h2pack(mv.z, bv.z, mv.w, bv.w);
            const int jj = c4 >> 1;
            ((uint2*)&BsT[row][jj ^ (row & 7)])[c4 & 1] = u;
        }
        __syncthreads();
        const int w = t >> 6, lane = t & 63, n = lane & 15, g = lane >> 4;
        const int row = w * 16 + n;
        #pragma unroll
        for (int tpl = 0; tpl < 2; ++tpl) {
            const int tp = half * 2 + tpl;
            const int jj = tpl * 4 + g;
            const uint4 v = BsT[row][jj ^ (row & 7)];
            const size_t ob = ((((size_t)(b * 16 + qt64) * 4 + w) * 8 + c) * 4 + tp) * 64 + lane;
            biasp[ob] = v;
        }
    } else if (blk < 2560) {
        const int base = (blk - 2048) * 1024;
        #pragma unroll
        for (int i = 0; i < 4; ++i) {
            const int i4 = base + t + i * 256;           // float4 index into K
            const float4 k = ((const float4*)K)[i4];
            uint2 o;
            o.x = pk_bf16(k.x, k.y);
            o.y = pk_bf16(k.z, k.w);
            KHI[i4] = o;
        }
    } else {
        __shared__ float Vs[64][17];
        const int vb = blk - 2560;                       // 0..511
        const int bh = vb >> 2;
        const int qq = vb & 3;
        #pragma unroll
        for (int st = 0; st < 4; ++st) {
            const int s0 = qq * 256 + st * 64;
            {
                const int row = t >> 2, c4 = t & 3;
                const float4 v = ((const float4*)V)[((size_t)bh * SEQ + s0 + row) * 4 + c4];
                Vs[row][c4 * 4 + 0] = v.x; Vs[row][c4 * 4 + 1] = v.y;
                Vs[row][c4 * 4 + 2] = v.z; Vs[row][c4 * 4 + 3] = v.w;
            }
            __syncthreads();
            const int d = t >> 4, sg = t & 15;
            short4v o;
            #pragma unroll
            for (int i = 0; i < 4; ++i) o[i] = (short)bf16_rne(Vs[sg * 4 + i][d]);
            ((short4v*)Vt)[(((size_t)bh * DK + d) * SEQ + s0) / 4 + sg] = o;
            __syncthreads();
        }
    }
}

// ---------------- Flash pass ------------------------------------------------
// Round-8: back to the verified round-0 structure (128 q/block, 2 frags/wave,
// grid 1024, CH=128 dbuf) — round-7 falsified the TLP theory (2x occupancy,
// slower). ONE change: QK's hi/lo split is computed as a single K=32 MFMA per
// key-tile instead of two K=16 MFMAs. score = sum_d K*qh + sum_d K*ql is a
// 32-deep contraction: m<16 -> (d,hi), m>=16 -> (d,lo). A-frag = K dims
// 8(g&1)..+7 (ds_read_b128; quads 2,3 broadcast-duplicate 0,1); B-frag =
// (g<2 ? qh : ql) same dims, built once. Halves QK matrix-pipe cycles and
// issues (K=16 shape runs at the K=32 shape's cycle cost on gfx950) and
// drops one serial MFMA from the Cinit->score->exp chain. Bit-identical math.
__global__ __launch_bounds__(256, 4)
void sdpa_flash(const float* __restrict__ Q, const uint2* __restrict__ KHI,
                const short* __restrict__ Vt, const uint4* __restrict__ biasp,
                float* __restrict__ out) {
    __shared__ __align__(16) char smem[2][BUF_SZ];

    const int tid  = threadIdx.x;
    const int wave = tid >> 6;
    const int lane = tid & 63;
    const int n    = lane & 15;
    const int g    = lane >> 4;
    const int permn = ((n >> 2) << 3) | (n & 3);   // tile-pair key permutation

    const int b  = blockIdx.x & 7;                 // XCD = batch
    const int j  = blockIdx.x >> 3;                // 0..127
    const int qt = j & 7;
    const int h  = j >> 3;                         // 0..15
    const int q0 = qt * 128;

    const size_t bh = (size_t)b * NHEAD + h;

    // 2 q-frags for K=32 QK: lane (n,g) holds (g<2 ? hi : lo) part of
    // Q[qrow][8(g&1) .. 8(g&1)+7], scaled by 0.25*LOG2E.
    short8v qf[2];
    size_t  bfbase[2];
    #pragma unroll
    for (int f = 0; f < 2; ++f) {
        const int qrow = q0 + f * 64 + wave * 16 + n;
        const float* qp = Q + (bh * SEQ + qrow) * DK + (g & 1) * 8;
        const float4 qv0 = *(const float4*)(qp);
        const float4 qv1 = *(const float4*)(qp + 4);
        const float qsc = 0.25f * LOG2E;
        const float v[8] = {qv0.x * qsc, qv0.y * qsc, qv0.z * qsc, qv0.w * qsc,
                            qv1.x * qsc, qv1.y * qsc, qv1.z * qsc, qv1.w * qsc};
        const bool hiPart = (g < 2);
        #pragma unroll
        for (int e = 0; e < 8; ++e) {
            const unsigned hu = bf16_rne(v[e]);
            const unsigned lo = bf16_rne(v[e] - bf16_to_f(hu));
            qf[f][e] = (short)(hiPart ? hu : lo);
        }
        bfbase[f] = (((size_t)(b * 16 + qt * 2 + f) * 4 + wave) * 32) * 64 + lane;
    }

    const uint4* KHIh = (const uint4*)(KHI + bh * SEQ * 4); // 2 uint4 per key row
    const uint4* VtH  = (const uint4*)(Vt + bh * DK * SEQ);

    float4v acc[2], accl[2];
    acc[0]  = (float4v){0.f, 0.f, 0.f, 0.f};
    acc[1]  = (float4v){0.f, 0.f, 0.f, 0.f};
    accl[0] = (float4v){0.f, 0.f, 0.f, 0.f};
    accl[1] = (float4v){0.f, 0.f, 0.f, 0.f};
    const short8v ones8 = {(short)0x3F80, (short)0x3F80, (short)0x3F80, (short)0x3F80,
                           (short)0x3F80, (short)0x3F80, (short)0x3F80, (short)0x3F80};

    // staging: K chunk = 256 uint4 (key = e>>1, half-row = e&1); V = 256 uint4
    uint4 st0, st2;
    {
        st0 = KHIh[tid];
        st2 = VtH[(tid >> 4) * 128 + (tid & 15)];
        char* s = smem[0];
        *(uint4*)(s + (tid >> 1) * KHI_STRIDE + (tid & 1) * 16) = st0;
        *(uint4*)(s + KHI_CH + (tid >> 4) * VT_STRIDE + (tid & 15) * 16) = st2;
    }
    __syncthreads();

    for (int c = 0; c < NCH; ++c) {
        const int cur = c & 1;
        if (c < NCH - 1) {
            st0 = KHIh[(c + 1) * 256 + tid];
            st2 = VtH[(tid >> 4) * 128 + (c + 1) * 16 + (tid & 15)];
        }
        uint4 bb[2][4];
        #pragma unroll
        for (int f = 0; f < 2; ++f)
            #pragma unroll
            for (int tp = 0; tp < 4; ++tp)
                bb[f][tp] = biasp[bfbase[f] + (size_t)(c * 4 + tp) * 64];

        const char* khl = smem[cur];
        const char* vtl = smem[cur] + KHI_CH;

        #pragma unroll
        for (int tp = 0; tp < 4; ++tp) {
            const int rowA = tp * 32 + permn;
            // A-frags: K dims 8(g&1)..+7 of key rows (quads 2,3 = broadcast of 0,1)
            const uint4 kAu = *(const uint4*)(khl + rowA * KHI_STRIDE + (g & 1) * 16);
            const uint4 kBu = *(const uint4*)(khl + (rowA + 4) * KHI_STRIDE + (g & 1) * 16);
            const uint4 vv  = *(const uint4*)(vtl + n * VT_STRIDE + tp * 64 + g * 16);
            const short8v khA = __builtin_bit_cast(short8v, kAu);
            const short8v khB = __builtin_bit_cast(short8v, kBu);
            const short8v vt8 = __builtin_bit_cast(short8v, vv);

            #pragma unroll
            for (int f = 0; f < 2; ++f) {
                // tile A scores: keys c*128 + tp*32 + 8g + r (one K=32 MFMA)
                const float2 a01 = __half22float2(__builtin_bit_cast(__half2, bb[f][tp].x));
                const float2 a23 = __half22float2(__builtin_bit_cast(__half2, bb[f][tp].y));
                float4v sA; sA[0] = a01.x; sA[1] = a01.y; sA[2] = a23.x; sA[3] = a23.y;
                sA = mfma32(khA, qf[f], sA);
                // tile B scores: keys c*128 + tp*32 + 8g + 4 + r
                const float2 b01 = __half22float2(__builtin_bit_cast(__half2, bb[f][tp].z));
                const float2 b23 = __half22float2(__builtin_bit_cast(__half2, bb[f][tp].w));
                float4v sB; sB[0] = b01.x; sB[1] = b01.y; sB[2] = b23.x; sB[3] = b23.y;
                sB = mfma32(khB, qf[f], sB);

                const float pA0 = fast_exp2(sA[0]), pA1 = fast_exp2(sA[1]);
                const float pA2 = fast_exp2(sA[2]), pA3 = fast_exp2(sA[3]);
                const float pB0 = fast_exp2(sB[0]), pB1 = fast_exp2(sB[1]);
                const float pB2 = fast_exp2(sB[2]), pB3 = fast_exp2(sB[3]);

                // K=32 A-frag: [pA0..3, pB0..3] == keys 8g..8g+7 (k = quad*8+j)
                uint4 pu;
                pu.x = pk_bf16(pA0, pA1);
                pu.y = pk_bf16(pA2, pA3);
                pu.z = pk_bf16(pB0, pB1);
                pu.w = pk_bf16(pB2, pB3);
                const short8v pf8 = __builtin_bit_cast(short8v, pu);

                acc[f]  = mfma32(pf8, vt8,  acc[f]);    // O += P*V   (32 keys)
                accl[f] = mfma32(pf8, ones8, accl[f]);  // l += sum_k P
            }
        }

        if (c < NCH - 1) {
            char* s = smem[cur ^ 1];
            *(uint4*)(s + (tid >> 1) * KHI_STRIDE + (tid & 1) * 16) = st0;
            *(uint4*)(s + KHI_CH + (tid >> 4) * VT_STRIDE + (tid & 15) * 16) = st2;
        }
        __syncthreads();
    }

    // epilogue: accl[f][r] == l for q-row 4g+r — no cross-lane traffic
    #pragma unroll
    for (int f = 0; f < 2; ++f) {
        const size_t obase = bh * SEQ + q0 + f * 64 + wave * 16;
        #pragma unroll
        for (int r = 0; r < 4; ++r) {
            out[(obase + 4 * g + r) * DK + n] = acc[f][r] / accl[f][r];
        }
    }
}

// ---------------- Fallback: single-pass scalar kernel (no workspace) ---------
#define FTQ 256
#define FTK 32
__global__ __launch_bounds__(256, 2)
void sdpa_fallback(const float* __restrict__ Q, const float* __restrict__ K,
                   const float* __restrict__ V, const int* __restrict__ mask,
                   const float* __restrict__ bias, float* __restrict__ out) {
    __shared__ float Ks[FTK][DK];
    __shared__ float Vs[FTK][DK];
    __shared__ float Bsf[FTQ][FTK + 1];

    const int tid = threadIdx.x;
    const int blk = blockIdx.x;
    const int h   = blk & (NHEAD - 1);
    const int qt  = (blk >> 4) & 3;
    const int b   = blk >> 6;
    const int q0  = qt * FTQ;
    const float qscale = 0.25f * LOG2E;
    const size_t bh = (size_t)b * NHEAD + h;

    float Qr[DK];
    {
        const float4* q4 = (const float4*)(Q + (bh * SEQ + q0 + tid) * DK);
        #pragma unroll
        for (int i = 0; i < 4; ++i) {
            float4 v = q4[i];
            Qr[4*i+0] = v.x * qscale; Qr[4*i+1] = v.y * qscale;
            Qr[4*i+2] = v.z * qscale; Qr[4*i+3] = v.w * qscale;
        }
    }
    float acc[DK];
    #pragma unroll
    for (int d = 0; d < DK; ++d) acc[d] = 0.0f;
    float l = 0.0f;

    const float* Kbase = K + bh * SEQ * DK;
    const float* Vbase = V + bh * SEQ * DK;
    const float* Bbase = bias + ((size_t)b * SEQ + q0) * SEQ;
    const int*   Mbase = mask + ((size_t)b * SEQ + q0) * SEQ;

    for (int t = 0; t < SEQ / FTK; ++t) {
        const int k0 = t * FTK;
        if (tid < 128) {
            float4 kv = ((const float4*)(Kbase + (size_t)k0 * DK))[tid];
            float4 vv = ((const float4*)(Vbase + (size_t)k0 * DK))[tid];
            ((float4*)&Ks[0][0])[tid] = kv;
            ((float4*)&Vs[0][0])[tid] = vv;
        }
        #pragma unroll
        for (int i = 0; i < 8; ++i) {
            int e4 = tid + i * 256, row = e4 >> 3, c4 = e4 & 7;
            const float4 bv = *(const float4*)(Bbase + (size_t)row * SEQ + k0 + c4 * 4);
            const int4   mv = *(const int4*)  (Mbase + (size_t)row * SEQ + k0 + c4 * 4);
            float* dst = &Bsf[row][c4 * 4];
            dst[0] = mv.x ? -1e9f : bv.x * LOG2E;
            dst[1] = mv.y ? -1e9f : bv.y * LOG2E;
            dst[2] = mv.z ? -1e9f : bv.z * LOG2E;
            dst[3] = mv.w ? -1e9f : bv.w * LOG2E;
        }
        __syncthreads();
        #pragma unroll 4
        for (int kk = 0; kk < FTK; ++kk) {
            float s = Bsf[tid][kk];
            const float4 k0v = *(const float4*)&Ks[kk][0];
            const float4 k1v = *(const float4*)&Ks[kk][4];
            const float4 k2v = *(const float4*)&Ks[kk][8];
            const float4 k3v = *(const float4*)&Ks[kk][12];
            s = fmaf(Qr[0],  k0v.x, s); s = fmaf(Qr[1],  k0v.y, s);
            s = fmaf(Qr[2],  k0v.z, s); s = fmaf(Qr[3],  k0v.w, s);
            s = fmaf(Qr[4],  k1v.x, s); s = fmaf(Qr[5],  k1v.y, s);
            s = fmaf(Qr[6],  k1v.z, s); s = fmaf(Qr[7],  k1v.w, s);
            s = fmaf(Qr[8],  k2v.x, s); s = fmaf(Qr[9],  k2v.y, s);
            s = fmaf(Qr[10], k2v.z, s); s = fmaf(Qr[11], k2v.w, s);
            s = fmaf(Qr[12], k3v.x, s); s = fmaf(Qr[13], k3v.y, s);
            s = fmaf(Qr[14], k3v.z, s); s = fmaf(Qr[15], k3v.w, s);
            float p = fast_exp2(s);
            l += p;
            const float4 v0 = *(const float4*)&Vs[kk][0];
            const float4 v1 = *(const float4*)&Vs[kk][4];
            const float4 v2 = *(const float4*)&Vs[kk][8];
            const float4 v3 = *(const float4*)&Vs[kk][12];
            acc[0]  = fmaf(p, v0.x, acc[0]);  acc[1]  = fmaf(p, v0.y, acc[1]);
            acc[2]  = fmaf(p, v0.z, acc[2]);  acc[3]  = fmaf(p, v0.w, acc[3]);
            acc[4]  = fmaf(p, v1.x, acc[4]);  acc[5]  = fmaf(p, v1.y, acc[5]);
            acc[6]  = fmaf(p, v1.z, acc[6]);  acc[7]  = fmaf(p, v1.w, acc[7]);
            acc[8]  = fmaf(p, v2.x, acc[8]);  acc[9]  = fmaf(p, v2.y, acc[9]);
            acc[10] = fmaf(p, v2.z, acc[10]); acc[11] = fmaf(p, v2.w, acc[11]);
            acc[12] = fmaf(p, v3.x, acc[12]); acc[13] = fmaf(p, v3.y, acc[13]);
            acc[14] = fmaf(p, v3.z, acc[14]); acc[15] = fmaf(p, v3.w, acc[15]);
        }
        __syncthreads();
    }
    const float inv = 1.0f / l;
    float4* o4 = (float4*)(out + (bh * SEQ + q0 + tid) * DK);
    #pragma unroll
    for (int i = 0; i < 4; ++i) {
        float4 v;
        v.x = acc[4*i+0] * inv; v.y = acc[4*i+1] * inv;
        v.z = acc[4*i+2] * inv; v.w = acc[4*i+3] * inv;
        o4[i] = v;
    }
}

extern "C" void kernel_launch(void* const* d_in, const int* in_sizes, int n_in,
                              void* d_out, int out_size, void* d_ws, size_t ws_size,
                              hipStream_t stream) {
    const float* Q    = (const float*)d_in[0];
    const float* K    = (const float*)d_in[1];
    const float* V    = (const float*)d_in[2];
    const int*   mask = (const int*)  d_in[3];
    const float* bias = (const float*)d_in[4];
    float* out = (float*)d_out;

    const size_t nKeys    = (size_t)NBATCH * NHEAD * SEQ;      // 131072
    const size_t khiBytes = nKeys * 32;                        // 4.19 MB
    const size_t vtBytes  = nKeys * DK * sizeof(short);        // 4.19 MB
    const size_t bpBytes  = (size_t)NBATCH * SEQ * SEQ * 2;    // 16.8 MB
    const size_t need     = khiBytes + vtBytes + bpBytes;      // 25.2 MB

    if (ws_size >= need) {
        char* w = (char*)d_ws;
        uint2* KHI   = (uint2*)(w);
        short* Vt    = (short*)(w + khiBytes);
        uint4* biasp = (uint4*)(w + khiBytes + vtBytes);

        prep_all<<<3072, 256, 0, stream>>>(K, V, mask, bias, KHI, Vt, biasp);
        sdpa_flash<<<1024, 256, 0, stream>>>(Q, KHI, Vt, biasp, out);
    } else {
        sdpa_fallback<<<NBATCH * NHEAD * (SEQ / FTQ), FTQ, 0, stream>>>(Q, K, V, mask, bias, out);
    }
}

// Round 9
// 153.047 us; speedup vs baseline: 1.6642x; 1.0698x over previous
//
#include <hip/hip_runtime.h>
#include <hip/hip_fp16.h>
#include <math.h>

#define SEQ    1024
#define DK     16
#define NHEAD  16
#define NBATCH 8
#define LOG2E  1.4426950408889634f

#define CH     128                       // keys per LDS chunk
#define NCH    (SEQ / CH)                // 8 chunks
#define KHI_STRIDE 40                    // LDS bytes per key row (32 data + 8 pad)
#define VT_STRIDE  272                   // LDS bytes per d row   (256 data + 16 pad)
#define KHI_CH (CH * KHI_STRIDE)         // 5120 B
#define VT_CH  (DK * VT_STRIDE)          // 4352 B
#define BUF_SZ (KHI_CH + VT_CH)          // 9472 B per buffer (x2 = 18.9 KB)

typedef __attribute__((ext_vector_type(4))) short  short4v;
typedef __attribute__((ext_vector_type(8))) short  short8v;
typedef __attribute__((ext_vector_type(2))) short  short2v;
typedef __attribute__((ext_vector_type(4))) float  float4v;
typedef __attribute__((ext_vector_type(2))) unsigned int uint2v;

static __device__ __forceinline__ float fast_exp2(float x) {
#if __has_builtin(__builtin_amdgcn_exp2f)
    return __builtin_amdgcn_exp2f(x);
#else
    return exp2f(x);
#endif
}

static __device__ __forceinline__ float4v mfma16(short4v a, short4v b, float4v c) {
#if __has_builtin(__builtin_amdgcn_mfma_f32_16x16x16bf16_1k)
    return __builtin_amdgcn_mfma_f32_16x16x16bf16_1k(a, b, c, 0, 0, 0);
#else
    float4v d = c;
    asm volatile("v_mfma_f32_16x16x16_bf16 %0, %1, %2, %0" : "+v"(d) : "v"(a), "v"(b));
    return d;
#endif
}

// K=32 MFMA: A/B = 8 bf16/lane (k = quad*8 + j). Fallback: two K=16 halves.
static __device__ __forceinline__ float4v mfma32(short8v a, short8v b, float4v c) {
#if __has_builtin(__builtin_amdgcn_mfma_f32_16x16x32_bf16)
    return __builtin_amdgcn_mfma_f32_16x16x32_bf16(a, b, c, 0, 0, 0);
#else
    short4v a0 = {a[0], a[1], a[2], a[3]}, a1 = {a[4], a[5], a[6], a[7]};
    short4v b0 = {b[0], b[1], b[2], b[3]}, b1 = {b[4], b[5], b[6], b[7]};
    c = mfma16(a0, b0, c);
    return mfma16(a1, b1, c);
#endif
}

static __device__ __forceinline__ unsigned bf16_rne(float x) {
    unsigned u = __float_as_uint(x);
    return (u + 0x7FFFu + ((u >> 16) & 1u)) >> 16;
}
static __device__ __forceinline__ float bf16_to_f(unsigned b) {
    return __uint_as_float(b << 16);
}
static __device__ __forceinline__ unsigned pk_bf16(float a, float b) {
#if __has_builtin(__builtin_amdgcn_cvt_pk_bf16_f32)
    short2v r = __builtin_amdgcn_cvt_pk_bf16_f32(a, b);
    return __builtin_bit_cast(unsigned, r);
#else
    return bf16_rne(a) | (bf16_rne(b) << 16);
#endif
}
static __device__ __forceinline__ short4v bc_s4(unsigned lo, unsigned hi) {
    uint2v u; u.x = lo; u.y = hi;
    return __builtin_bit_cast(short4v, u);
}
static __device__ __forceinline__ unsigned h2pack(int m0, float b0, int m1, float b1) {
    const __half2 a = __floats2half2_rn(m0 ? -60000.f : b0 * LOG2E,
                                        m1 ? -60000.f : b1 * LOG2E);
    return __builtin_bit_cast(unsigned, a);
}

// ---------------- Prep (one kernel, 3 jobs by block range) -------------------
// [0,2048):     bias+mask -> biasp fp16 fragment-major (64q x 64k per block)
// [2048,2560):  K -> Khi bf16 (plain rounding, 32 B per key row)
// [2560,3072):  V -> Vt bf16 [B*H][d][s]
__global__ __launch_bounds__(256)
void prep_all(const float* __restrict__ K, const float* __restrict__ V,
              const int* __restrict__ mask, const float* __restrict__ bias,
              uint2* __restrict__ KHI, short* __restrict__ Vt,
              uint4* __restrict__ biasp) {
    const int blk = blockIdx.x;
    const int t   = threadIdx.x;
    if (blk < 2048) {
        __shared__ uint4 BsT[64][9];
        const int b    = blk >> 8;
        const int qt64 = (blk >> 4) & 15;
        const int c    = (blk >> 1) & 7;
        const int half = blk & 1;
        const int kb   = c * 128 + half * 64;
        #pragma unroll
        for (int i = 0; i < 4; ++i) {
            const int idx = t + i * 256;                 // 0..1023
            const int row = idx >> 4;                    // q-local 0..63
            const int c4  = idx & 15;                    // float4 col in 64-k window
            const size_t ga = ((size_t)b * SEQ + qt64 * 64 + row) * SEQ + kb + c4 * 4;
            const float4 bv = *(const float4*)(bias + ga);
            const int4   mv = *(const int4*)(mask + ga);
            uint2 u;
            u.x = h2pack(mv.x, bv.x, mv.y, bv.y);
            u.y = h2pack(mv.z, bv.z, mv.w, bv.w);
            const int jj = c4 >> 1;
            ((uint2*)&BsT[row][jj ^ (row & 7)])[c4 & 1] = u;
        }
        __syncthreads();
        const int w = t >> 6, lane = t & 63, n = lane & 15, g = lane >> 4;
        const int row = w * 16 + n;
        #pragma unroll
        for (int tpl = 0; tpl < 2; ++tpl) {
            const int tp = half * 2 + tpl;
            const int jj = tpl * 4 + g;
            const uint4 v = BsT[row][jj ^ (row & 7)];
            const size_t ob = ((((size_t)(b * 16 + qt64) * 4 + w) * 8 + c) * 4 + tp) * 64 + lane;
            biasp[ob] = v;
        }
    } else if (blk < 2560) {
        const int base = (blk - 2048) * 1024;
        #pragma unroll
        for (int i = 0; i < 4; ++i) {
            const int i4 = base + t + i * 256;           // float4 index into K
            const float4 k = ((const float4*)K)[i4];
            uint2 o;
            o.x = pk_bf16(k.x, k.y);
            o.y = pk_bf16(k.z, k.w);
            KHI[i4] = o;
        }
    } else {
        __shared__ float Vs[64][17];
        const int vb = blk - 2560;                       // 0..511
        const int bh = vb >> 2;
        const int qq = vb & 3;
        #pragma unroll
        for (int st = 0; st < 4; ++st) {
            const int s0 = qq * 256 + st * 64;
            {
                const int row = t >> 2, c4 = t & 3;
                const float4 v = ((const float4*)V)[((size_t)bh * SEQ + s0 + row) * 4 + c4];
                Vs[row][c4 * 4 + 0] = v.x; Vs[row][c4 * 4 + 1] = v.y;
                Vs[row][c4 * 4 + 2] = v.z; Vs[row][c4 * 4 + 3] = v.w;
            }
            __syncthreads();
            const int d = t >> 4, sg = t & 15;
            short4v o;
            #pragma unroll
            for (int i = 0; i < 4; ++i) o[i] = (short)bf16_rne(Vs[sg * 4 + i][d]);
            ((short4v*)Vt)[(((size_t)bh * DK + d) * SEQ + s0) / 4 + sg] = o;
            __syncthreads();
        }
    }
}

// ---------------- Flash pass ------------------------------------------------
// Round-9: byte-exact round-0 structure (the verified 43-us kernel; rounds 7/8
// falsified the TLP and MFMA-merge theories). ONE change: biasp fragment
// loads (bb) are issued at the END of the chunk that last consumed them,
// prefetching chunk c+1 — round-0 issued them ~10 instructions above their
// first use (MFMA C-init), exposing L2/L3 latency once per chunk per wave.
// The loads now fly across ds_write staging + __syncthreads + the next
// chunk's LDS reads. sched_barrier(0) pins them (round-2 showed plain reg
// prefetches get sunk to their consumers; round-4 showed this fence holds).
__global__ __launch_bounds__(256, 4)
void sdpa_flash(const float* __restrict__ Q, const uint2* __restrict__ KHI,
                const short* __restrict__ Vt, const uint4* __restrict__ biasp,
                float* __restrict__ out) {
    __shared__ __align__(16) char smem[2][BUF_SZ];

    const int tid  = threadIdx.x;
    const int wave = tid >> 6;
    const int lane = tid & 63;
    const int n    = lane & 15;
    const int g    = lane >> 4;
    const int permn = ((n >> 2) << 3) | (n & 3);   // tile-pair key permutation

    const int b  = blockIdx.x & 7;                 // XCD = batch
    const int j  = blockIdx.x >> 3;                // 0..127
    const int qt = j & 7;
    const int h  = j >> 3;                         // 0..15
    const int q0 = qt * 128;

    const size_t bh = (size_t)b * NHEAD + h;

    // 2 q-frags: q = q0 + f*64 + wave*16 + n
    short4v qh[2], ql[2];
    size_t  bfbase[2];
    #pragma unroll
    for (int f = 0; f < 2; ++f) {
        const int qrow = q0 + f * 64 + wave * 16 + n;
        const float4 qv = *(const float4*)(Q + (bh * SEQ + qrow) * DK + g * 4);
        const float qsc = 0.25f * LOG2E;
        const float v[4] = {qv.x * qsc, qv.y * qsc, qv.z * qsc, qv.w * qsc};
        #pragma unroll
        for (int e = 0; e < 4; ++e) {
            const unsigned hu = bf16_rne(v[e]);
            qh[f][e] = (short)hu;
            ql[f][e] = (short)bf16_rne(v[e] - bf16_to_f(hu));
        }
        bfbase[f] = (((size_t)(b * 16 + qt * 2 + f) * 4 + wave) * 32) * 64 + lane;
    }

    const uint4* KHIh = (const uint4*)(KHI + bh * SEQ * 4); // 2 uint4 per key row
    const uint4* VtH  = (const uint4*)(Vt + bh * DK * SEQ);

    float4v acc[2], accl[2];
    acc[0]  = (float4v){0.f, 0.f, 0.f, 0.f};
    acc[1]  = (float4v){0.f, 0.f, 0.f, 0.f};
    accl[0] = (float4v){0.f, 0.f, 0.f, 0.f};
    accl[1] = (float4v){0.f, 0.f, 0.f, 0.f};
    const short8v ones8 = {(short)0x3F80, (short)0x3F80, (short)0x3F80, (short)0x3F80,
                           (short)0x3F80, (short)0x3F80, (short)0x3F80, (short)0x3F80};

    // biasp fragments for the CURRENT chunk, prefetched one chunk ahead.
    uint4 bb[2][4];
    #pragma unroll
    for (int f = 0; f < 2; ++f)
        #pragma unroll
        for (int tp = 0; tp < 4; ++tp)
            bb[f][tp] = biasp[bfbase[f] + (size_t)tp * 64];   // chunk 0

    // staging: K chunk = 256 uint4 (key = e>>1, half-row = e&1); V = 256 uint4
    uint4 st0, st2;
    {
        st0 = KHIh[tid];
        st2 = VtH[(tid >> 4) * 128 + (tid & 15)];
        char* s = smem[0];
        *(uint4*)(s + (tid >> 1) * KHI_STRIDE + (tid & 1) * 16) = st0;
        *(uint4*)(s + KHI_CH + (tid >> 4) * VT_STRIDE + (tid & 15) * 16) = st2;
    }
    __syncthreads();

    for (int c = 0; c < NCH; ++c) {
        const int cur = c & 1;
        if (c < NCH - 1) {
            st0 = KHIh[(c + 1) * 256 + tid];
            st2 = VtH[(tid >> 4) * 128 + (c + 1) * 16 + (tid & 15)];
        }

        const char* khl = smem[cur];
        const char* vtl = smem[cur] + KHI_CH;

        #pragma unroll
        for (int tp = 0; tp < 4; ++tp) {
            const int rowA = tp * 32 + permn;
            const uint2 kAu = *(const uint2*)(khl + rowA * KHI_STRIDE + g * 8);
            const uint2 kBu = *(const uint2*)(khl + (rowA + 4) * KHI_STRIDE + g * 8);
            const uint4 vv  = *(const uint4*)(vtl + n * VT_STRIDE + tp * 64 + g * 16);
            const short4v khiA = bc_s4(kAu.x, kAu.y);
            const short4v khiB = bc_s4(kBu.x, kBu.y);
            const short8v vt8  = __builtin_bit_cast(short8v, vv);

            #pragma unroll
            for (int f = 0; f < 2; ++f) {
                // tile A scores: keys c*128 + tp*32 + 8g + r
                const float2 a01 = __half22float2(__builtin_bit_cast(__half2, bb[f][tp].x));
                const float2 a23 = __half22float2(__builtin_bit_cast(__half2, bb[f][tp].y));
                float4v sA; sA[0] = a01.x; sA[1] = a01.y; sA[2] = a23.x; sA[3] = a23.y;
                sA = mfma16(khiA, qh[f], sA);
                sA = mfma16(khiA, ql[f], sA);
                // tile B scores: keys c*128 + tp*32 + 8g + 4 + r
                const float2 b01 = __half22float2(__builtin_bit_cast(__half2, bb[f][tp].z));
                const float2 b23 = __half22float2(__builtin_bit_cast(__half2, bb[f][tp].w));
                float4v sB; sB[0] = b01.x; sB[1] = b01.y; sB[2] = b23.x; sB[3] = b23.y;
                sB = mfma16(khiB, qh[f], sB);
                sB = mfma16(khiB, ql[f], sB);

                const float pA0 = fast_exp2(sA[0]), pA1 = fast_exp2(sA[1]);
                const float pA2 = fast_exp2(sA[2]), pA3 = fast_exp2(sA[3]);
                const float pB0 = fast_exp2(sB[0]), pB1 = fast_exp2(sB[1]);
                const float pB2 = fast_exp2(sB[2]), pB3 = fast_exp2(sB[3]);

                // K=32 A-frag: [pA0..3, pB0..3] == keys 8g..8g+7 (k = quad*8+j)
                uint4 pu;
                pu.x = pk_bf16(pA0, pA1);
                pu.y = pk_bf16(pA2, pA3);
                pu.z = pk_bf16(pB0, pB1);
                pu.w = pk_bf16(pB2, pB3);
                const short8v pf8 = __builtin_bit_cast(short8v, pu);

                acc[f]  = mfma32(pf8, vt8,  acc[f]);    // O += P*V   (32 keys)
                accl[f] = mfma32(pf8, ones8, accl[f]);  // l += sum_k P
            }
        }

        if (c < NCH - 1) {
            // prefetch next chunk's bias fragments NOW (last use of bb was
            // above); results land during ds_writes + barrier + next LDS reads
            #pragma unroll
            for (int f = 0; f < 2; ++f)
                #pragma unroll
                for (int tp = 0; tp < 4; ++tp)
                    bb[f][tp] = biasp[bfbase[f] + (size_t)((c + 1) * 4 + tp) * 64];
#if __has_builtin(__builtin_amdgcn_sched_barrier)
            __builtin_amdgcn_sched_barrier(0);   // don't sink past the barrier
#endif
            char* s = smem[cur ^ 1];
            *(uint4*)(s + (tid >> 1) * KHI_STRIDE + (tid & 1) * 16) = st0;
            *(uint4*)(s + KHI_CH + (tid >> 4) * VT_STRIDE + (tid & 15) * 16) = st2;
        }
        __syncthreads();
    }

    // epilogue: accl[f][r] == l for q-row 4g+r — no cross-lane traffic
    #pragma unroll
    for (int f = 0; f < 2; ++f) {
        const size_t obase = bh * SEQ + q0 + f * 64 + wave * 16;
        #pragma unroll
        for (int r = 0; r < 4; ++r) {
            out[(obase + 4 * g + r) * DK + n] = acc[f][r] / accl[f][r];
        }
    }
}

// ---------------- Fallback: single-pass scalar kernel (no workspace) ---------
#define FTQ 256
#define FTK 32
__global__ __launch_bounds__(256, 2)
void sdpa_fallback(const float* __restrict__ Q, const float* __restrict__ K,
                   const float* __restrict__ V, const int* __restrict__ mask,
                   const float* __restrict__ bias, float* __restrict__ out) {
    __shared__ float Ks[FTK][DK];
    __shared__ float Vs[FTK][DK];
    __shared__ float Bsf[FTQ][FTK + 1];

    const int tid = threadIdx.x;
    const int blk = blockIdx.x;
    const int h   = blk & (NHEAD - 1);
    const int qt  = (blk >> 4) & 3;
    const int b   = blk >> 6;
    const int q0  = qt * FTQ;
    const float qscale = 0.25f * LOG2E;
    const size_t bh = (size_t)b * NHEAD + h;

    float Qr[DK];
    {
        const float4* q4 = (const float4*)(Q + (bh * SEQ + q0 + tid) * DK);
        #pragma unroll
        for (int i = 0; i < 4; ++i) {
            float4 v = q4[i];
            Qr[4*i+0] = v.x * qscale; Qr[4*i+1] = v.y * qscale;
            Qr[4*i+2] = v.z * qscale; Qr[4*i+3] = v.w * qscale;
        }
    }
    float acc[DK];
    #pragma unroll
    for (int d = 0; d < DK; ++d) acc[d] = 0.0f;
    float l = 0.0f;

    const float* Kbase = K + bh * SEQ * DK;
    const float* Vbase = V + bh * SEQ * DK;
    const float* Bbase = bias + ((size_t)b * SEQ + q0) * SEQ;
    const int*   Mbase = mask + ((size_t)b * SEQ + q0) * SEQ;

    for (int t = 0; t < SEQ / FTK; ++t) {
        const int k0 = t * FTK;
        if (tid < 128) {
            float4 kv = ((const float4*)(Kbase + (size_t)k0 * DK))[tid];
            float4 vv = ((const float4*)(Vbase + (size_t)k0 * DK))[tid];
            ((float4*)&Ks[0][0])[tid] = kv;
            ((float4*)&Vs[0][0])[tid] = vv;
        }
        #pragma unroll
        for (int i = 0; i < 8; ++i) {
            int e4 = tid + i * 256, row = e4 >> 3, c4 = e4 & 7;
            const float4 bv = *(const float4*)(Bbase + (size_t)row * SEQ + k0 + c4 * 4);
            const int4   mv = *(const int4*)  (Mbase + (size_t)row * SEQ + k0 + c4 * 4);
            float* dst = &Bsf[row][c4 * 4];
            dst[0] = mv.x ? -1e9f : bv.x * LOG2E;
            dst[1] = mv.y ? -1e9f : bv.y * LOG2E;
            dst[2] = mv.z ? -1e9f : bv.z * LOG2E;
            dst[3] = mv.w ? -1e9f : bv.w * LOG2E;
        }
        __syncthreads();
        #pragma unroll 4
        for (int kk = 0; kk < FTK; ++kk) {
            float s = Bsf[tid][kk];
            const float4 k0v = *(const float4*)&Ks[kk][0];
            const float4 k1v = *(const float4*)&Ks[kk][4];
            const float4 k2v = *(const float4*)&Ks[kk][8];
            const float4 k3v = *(const float4*)&Ks[kk][12];
            s = fmaf(Qr[0],  k0v.x, s); s = fmaf(Qr[1],  k0v.y, s);
            s = fmaf(Qr[2],  k0v.z, s); s = fmaf(Qr[3],  k0v.w, s);
            s = fmaf(Qr[4],  k1v.x, s); s = fmaf(Qr[5],  k1v.y, s);
            s = fmaf(Qr[6],  k1v.z, s); s = fmaf(Qr[7],  k1v.w, s);
            s = fmaf(Qr[8],  k2v.x, s); s = fmaf(Qr[9],  k2v.y, s);
            s = fmaf(Qr[10], k2v.z, s); s = fmaf(Qr[11], k2v.w, s);
            s = fmaf(Qr[12], k3v.x, s); s = fmaf(Qr[13], k3v.y, s);
            s = fmaf(Qr[14], k3v.z, s); s = fmaf(Qr[15], k3v.w, s);
            float p = fast_exp2(s);
            l += p;
            const float4 v0 = *(const float4*)&Vs[kk][0];
            const float4 v1 = *(const float4*)&Vs[kk][4];
            const float4 v2 = *(const float4*)&Vs[kk][8];
            const float4 v3 = *(const float4*)&Vs[kk][12];
            acc[0]  = fmaf(p, v0.x, acc[0]);  acc[1]  = fmaf(p, v0.y, acc[1]);
            acc[2]  = fmaf(p, v0.z, acc[2]);  acc[3]  = fmaf(p, v0.w, acc[3]);
            acc[4]  = fmaf(p, v1.x, acc[4]);  acc[5]  = fmaf(p, v1.y, acc[5]);
            acc[6]  = fmaf(p, v1.z, acc[6]);  acc[7]  = fmaf(p, v1.w, acc[7]);
            acc[8]  = fmaf(p, v2.x, acc[8]);  acc[9]  = fmaf(p, v2.y, acc[9]);
            acc[10] = fmaf(p, v2.z, acc[10]); acc[11] = fmaf(p, v2.w, acc[11]);
            acc[12] = fmaf(p, v3.x, acc[12]); acc[13] = fmaf(p, v3.y, acc[13]);
            acc[14] = fmaf(p, v3.z, acc[14]); acc[15] = fmaf(p, v3.w, acc[15]);
        }
        __syncthreads();
    }
    const float inv = 1.0f / l;
    float4* o4 = (float4*)(out + (bh * SEQ + q0 + tid) * DK);
    #pragma unroll
    for (int i = 0; i < 4; ++i) {
        float4 v;
        v.x = acc[4*i+0] * inv; v.y = acc[4*i+1] * inv;
        v.z = acc[4*i+2] * inv; v.w = acc[4*i+3] * inv;
        o4[i] = v;
    }
}

extern "C" void kernel_launch(void* const* d_in, const int* in_sizes, int n_in,
                              void* d_out, int out_size, void* d_ws, size_t ws_size,
                              hipStream_t stream) {
    const float* Q    = (const float*)d_in[0];
    const float* K    = (const float*)d_in[1];
    const float* V    = (const float*)d_in[2];
    const int*   mask = (const int*)  d_in[3];
    const float* bias = (const float*)d_in[4];
    float* out = (float*)d_out;

    const size_t nKeys    = (size_t)NBATCH * NHEAD * SEQ;      // 131072
    const size_t khiBytes = nKeys * 32;                        // 4.19 MB
    const size_t vtBytes  = nKeys * DK * sizeof(short);        // 4.19 MB
    const size_t bpBytes  = (size_t)NBATCH * SEQ * SEQ * 2;    // 16.8 MB
    const size_t need     = khiBytes + vtBytes + bpBytes;      // 25.2 MB

    if (ws_size >= need) {
        char* w = (char*)d_ws;
        uint2* KHI   = (uint2*)(w);
        short* Vt    = (short*)(w + khiBytes);
        uint4* biasp = (uint4*)(w + khiBytes + vtBytes);

        prep_all<<<3072, 256, 0, stream>>>(K, V, mask, bias, KHI, Vt, biasp);
        sdpa_flash<<<1024, 256, 0, stream>>>(Q, KHI, Vt, biasp, out);
    } else {
        sdpa_fallback<<<NBATCH * NHEAD * (SEQ / FTQ), FTQ, 0, stream>>>(Q, K, V, mask, bias, out);
    }
}